// Round 4
// baseline (332.576 us; speedup 1.0000x reference)
//
#include <hip/hip_runtime.h>
#include <math.h>

#define NQ 256
#define NK 65536
#define DD 3072
#define TOPK 10
#define BN 64
#define BK 64
#define KTILES (DD / BK)              // 48
#define ATILE_BYTES (256 * BK * 2)    // 32768 B per k-tile bf16 image
#define CPB 8                         // candidates kept per query per block

typedef unsigned long long u64;
typedef unsigned int u32;
typedef unsigned short u16;

typedef __attribute__((ext_vector_type(8))) short short8;   // bf16x8 MFMA frag
typedef __attribute__((ext_vector_type(4))) float f32x4;
typedef __attribute__((ext_vector_type(4))) unsigned short us4;

#define GLDS(src, dst)                                                        \
  __builtin_amdgcn_global_load_lds(                                           \
      (const __attribute__((address_space(1))) void*)(src),                   \
      (__attribute__((address_space(3))) void*)(dst), 16, 0, 0)

__device__ __forceinline__ float fixv(float x) {
  if (isnan(x)) return 0.0f;
  if (isinf(x)) return x > 0.0f ? 1.0f : -1.0f;
  return x;
}

// RNE float -> bf16 bits
__device__ __forceinline__ u16 f2bf(float x) {
  u32 u = __float_as_uint(x);
  u32 r = (u + 0x7fffu + ((u >> 16) & 1u)) >> 16;
  return (u16)r;
}

// Order-preserving map: larger score -> larger key; ties -> smaller idx wins.
__device__ __forceinline__ u64 makekey(float f, int idx) {
  u32 u = __float_as_uint(f);
  u = (u & 0x80000000u) ? ~u : (u | 0x80000000u);
  return ((u64)u << 32) | (u32)(~(u32)idx);
}

// Same map for bf16-bit scores (monotone: RNE rounding preserves order; ties -> idx)
__device__ __forceinline__ u64 skey(u16 bf, int idx) {
  u32 s = ((u32)bf) << 16;
  s = (s & 0x80000000u) ? ~s : (s | 0x80000000u);
  return ((u64)s << 32) | (u32)(~(u32)idx);
}

// ---------- kernel 1: nan_to_num + normalize queries ----------
// Outputs: qn fp32 (rescore) + pre-swizzled bf16 A-tile image (GEMM staging)
__global__ __launch_bounds__(256) void qnorm_kernel(const float* __restrict__ query,
                                                    float* __restrict__ qn,
                                                    u16* __restrict__ apre) {
  const int m = blockIdx.x;
  const int t = threadIdx.x;
  const float4* qp = (const float4*)(query + (size_t)m * DD);
  float4 v[3];
  float s = 0.0f;
#pragma unroll
  for (int i = 0; i < 3; ++i) {
    float4 x = qp[t + i * 256];
    x.x = fixv(x.x); x.y = fixv(x.y); x.z = fixv(x.z); x.w = fixv(x.w);
    v[i] = x;
    s += x.x * x.x + x.y * x.y + x.z * x.z + x.w * x.w;
  }
#pragma unroll
  for (int off = 32; off > 0; off >>= 1) s += __shfl_xor(s, off);
  __shared__ float red[4];
  if ((t & 63) == 0) red[t >> 6] = s;
  __syncthreads();
  float inv = 1.0f / fmaxf(sqrtf(red[0] + red[1] + red[2] + red[3]), 1e-12f);
#pragma unroll
  for (int i = 0; i < 3; ++i) {
    float4 x = v[i];
    x.x *= inv; x.y *= inv; x.z *= inv; x.w *= inv;
    ((float4*)(qn + (size_t)m * DD))[t + i * 256] = x;
    // pre-swizzled bf16 image: tile kt, row m (128 B), byte ^= (m&7)<<4
    int k0 = (t + i * 256) * 4;
    int kt = k0 >> 6;
    int kk = k0 & 63;
    u32 off = (u32)kt * ATILE_BYTES + (((u32)(m * 128 + kk * 2)) ^ (((u32)m & 7) << 4));
    us4 b;
    b.x = f2bf(x.x); b.y = f2bf(x.y); b.z = f2bf(x.z); b.w = f2bf(x.w);
    *(us4*)((char*)apre + off) = b;
  }
}

// ---------- kernel 2: bf16 MFMA GEMM + fused key-norm + fused per-block top-8 ----------
// BM=256 (all queries) x BN=64 keys per block; keys read once from HBM.
// B prefetched into registers one tile ahead (issued after the barrier so the
// loads ride out the MFMA phase). Epilogue: scores -> LDS (bf16, swizzled) ->
// per-thread (one query each) serial top-8 -> cand[q][bid][0..7].
__global__ __launch_bounds__(256, 3) void gemm_topk(const u16* __restrict__ apre,
                                                    const float* __restrict__ keys,
                                                    float* __restrict__ invk,
                                                    u64* __restrict__ cand) {
  __shared__ __align__(16) u16 As[256 * BK];  // 32 KB; reused for score rows
  __shared__ __align__(16) u16 Bs[BN * BK];   // 8 KB
  __shared__ float sinv[BN];
  const int t = threadIdx.x;
  const int w = t >> 6, l = t & 63;
  const int n0 = blockIdx.x * BN;

  f32x4 acc[4][4];
#pragma unroll
  for (int mi = 0; mi < 4; ++mi)
#pragma unroll
    for (int ni = 0; ni < 4; ++ni) acc[mi][ni] = (f32x4){0.f, 0.f, 0.f, 0.f};
  float ssq[4] = {0.f, 0.f, 0.f, 0.f};

  const int br = t >> 4;        // 0..15
  const int bc = (t & 15) * 4;  // fp32 col {0,4,...,60}

  // prologue: prefetch tile 0's B into registers
  float4 bpf[4];
#pragma unroll
  for (int i = 0; i < 4; ++i)
    bpf[i] = *(const float4*)(keys + (size_t)(n0 + i * 16 + br) * DD + bc);

  for (int kt = 0; kt < KTILES; ++kt) {
    __syncthreads();  // previous tile's LDS reads complete
    // A tile: 32 KB async DMA from pre-swizzled image
    const char* asrc = (const char*)apre + (size_t)kt * ATILE_BYTES;
#pragma unroll
    for (int i = 0; i < 8; ++i)
      GLDS(asrc + i * 4096 + t * 16, (char*)As + i * 4096 + t * 16);
    // B tile from prefetch regs: ssq + bf16 -> swizzled LDS
#pragma unroll
    for (int i = 0; i < 4; ++i) {
      float4 v = bpf[i];
      ssq[i] += v.x * v.x + v.y * v.y + v.z * v.z + v.w * v.w;
      us4 b;
      b.x = f2bf(v.x); b.y = f2bf(v.y); b.z = f2bf(v.z); b.w = f2bf(v.w);
      int row = i * 16 + br;
      u32 off = ((u32)(row * 128 + bc * 2)) ^ (((u32)row & 7) << 4);
      *(us4*)((char*)Bs + off) = b;
    }
    __syncthreads();  // DMA + ds_writes visible
    // issue next tile's B loads now: they overlap the MFMA phase
    if (kt < KTILES - 1) {
      const int kb = (kt + 1) * BK;
#pragma unroll
      for (int i = 0; i < 4; ++i)
        bpf[i] = *(const float4*)(keys + (size_t)(n0 + i * 16 + br) * DD + kb + bc);
    }
#pragma unroll
    for (int ks = 0; ks < 2; ++ks) {
      short8 a[4], b[4];
#pragma unroll
      for (int mi = 0; mi < 4; ++mi) {
        int row = w * 64 + mi * 16 + (l & 15);
        u32 off = ((u32)(row * 128 + ks * 64 + (l >> 4) * 16)) ^ (((u32)row & 7) << 4);
        a[mi] = *(const short8*)((const char*)As + off);
      }
#pragma unroll
      for (int ni = 0; ni < 4; ++ni) {
        int row = ni * 16 + (l & 15);
        u32 off = ((u32)(row * 128 + ks * 64 + (l >> 4) * 16)) ^ (((u32)row & 7) << 4);
        b[ni] = *(const short8*)((const char*)Bs + off);
      }
#pragma unroll
      for (int mi = 0; mi < 4; ++mi)
#pragma unroll
        for (int ni = 0; ni < 4; ++ni)
          acc[mi][ni] = __builtin_amdgcn_mfma_f32_16x16x32_bf16(a[mi], b[ni], acc[mi][ni], 0, 0, 0);
    }
  }

  // key inverse norms
#pragma unroll
  for (int i = 0; i < 4; ++i) {
    float s = ssq[i];
    s += __shfl_xor(s, 1); s += __shfl_xor(s, 2);
    s += __shfl_xor(s, 4); s += __shfl_xor(s, 8);
    ssq[i] = s;
  }
  if ((t & 15) == 0) {
#pragma unroll
    for (int i = 0; i < 4; ++i) {
      int row = i * 16 + br;
      float iv = 1.0f / fmaxf(sqrtf(ssq[i]), 1e-12f);
      sinv[row] = iv;
      invk[n0 + row] = iv;  // unique writer: this block owns these keys
    }
  }
  __syncthreads();  // all waves done reading As; sinv visible

  // write bf16 scores into As-alias: [q][key] u16, byte ^= (q&7)<<4
  // C frag: col=lane&15, row=(lane>>4)*4+r
#pragma unroll
  for (int ni = 0; ni < 4; ++ni) {
    int nl = ni * 16 + (l & 15);
    float iv = sinv[nl];
#pragma unroll
    for (int mi = 0; mi < 4; ++mi) {
      int qb = w * 64 + mi * 16 + (l >> 4) * 4;
#pragma unroll
      for (int r = 0; r < 4; ++r) {
        int q = qb + r;
        u16 bf = f2bf(acc[mi][ni][r] * iv);
        u32 off = ((u32)(q * 128 + nl * 2)) ^ (((u32)q & 7) << 4);
        *(u16*)((char*)As + off) = bf;
      }
    }
  }
  __syncthreads();

  // per-thread: top-8 of query-row t (64 bf16 scores), static-indexed list
  u64 c8[CPB];
  {
    short8 v = *(const short8*)((const char*)As + (((u32)(t * 128)) ^ (((u32)t & 7) << 4)));
#pragma unroll
    for (int j = 0; j < 8; ++j) c8[j] = skey((u16)v[j], n0 + j);
  }
  u64 mn = c8[0];
#pragma unroll
  for (int i = 1; i < CPB; ++i) mn = c8[i] < mn ? c8[i] : mn;
#pragma unroll
  for (int c = 1; c < 8; ++c) {
    short8 v = *(const short8*)((const char*)As + (((u32)(t * 128 + c * 16)) ^ (((u32)t & 7) << 4)));
#pragma unroll
    for (int j = 0; j < 8; ++j) {
      u64 kk = skey((u16)v[j], n0 + c * 8 + j);
      if (kk > mn) {
#pragma unroll
        for (int q = 0; q < CPB; ++q)
          if (c8[q] == mn) c8[q] = kk;  // keys distinct -> unique match
        u64 m2 = c8[0];
#pragma unroll
        for (int q = 1; q < CPB; ++q) m2 = c8[q] < m2 ? c8[q] : m2;
        mn = m2;
      }
    }
  }
  // cand[q][bid][i]: merge kernel reads coalesced
  u64* cp = cand + ((size_t)t * (NK / BN) + blockIdx.x) * CPB;
#pragma unroll
  for (int i = 0; i < CPB; ++i) cp[i] = c8[i];
}

// ---------- kernel 3: merge 8192 cands -> top-16 -> exact rescore -> top-10 + gather ----------
__global__ __launch_bounds__(256) void merge_rescore(const u64* __restrict__ cand,
                                                     const float* __restrict__ qn,
                                                     const float* __restrict__ keys,
                                                     const float* __restrict__ invk,
                                                     float* __restrict__ out_emb,
                                                     float* __restrict__ out_idx) {
  const int b = blockIdx.x;
  const int t = threadIdx.x;
  const int w = t >> 6, l = t & 63;
  __shared__ u64 wtop[64];
  __shared__ u64 top16[16];
  __shared__ float exact[16];
  __shared__ int ord[TOPK];

  // thread-local top-16 of its 32 contiguous candidates (coalesced reads)
  const u64* cb = cand + (size_t)b * (NK / BN) * CPB;
  u64 c16[16];
#pragma unroll
  for (int i = 0; i < 16; ++i) c16[i] = cb[t * 32 + i];
  u64 mn = c16[0];
#pragma unroll
  for (int i = 1; i < 16; ++i) mn = c16[i] < mn ? c16[i] : mn;
#pragma unroll
  for (int i = 16; i < 32; ++i) {
    u64 kk = cb[t * 32 + i];
    if (kk > mn) {
#pragma unroll
      for (int q = 0; q < 16; ++q)
        if (c16[q] == mn) c16[q] = kk;
      u64 m2 = c16[0];
#pragma unroll
      for (int q = 1; q < 16; ++q) m2 = c16[q] < m2 ? c16[q] : m2;
      mn = m2;
    }
  }
  // wave-level top-16 (16 rounds shfl-max, owner clears; entries distinct)
#pragma unroll 1
  for (int r = 0; r < 16; ++r) {
    u64 best = 0;
#pragma unroll
    for (int i = 0; i < 16; ++i) best = c16[i] > best ? c16[i] : best;
    u64 wb = best;
#pragma unroll
    for (int off = 1; off < 64; off <<= 1) {
      u64 o = __shfl_xor(wb, off);
      wb = o > wb ? o : wb;
    }
#pragma unroll
    for (int i = 0; i < 16; ++i)
      if (c16[i] == wb) c16[i] = 0;
    if (l == 0) wtop[w * 16 + r] = wb;
  }
  __syncthreads();
  if (w == 0) {  // wave 0: merge 4x16 -> global top-16
    u64 e = wtop[l];
#pragma unroll 1
    for (int r = 0; r < 16; ++r) {
      u64 wb = e;
#pragma unroll
      for (int off = 1; off < 64; off <<= 1) {
        u64 o = __shfl_xor(wb, off);
        wb = o > wb ? o : wb;
      }
      if (e == wb) e = 0;
      if (l == 0) top16[r] = wb;
    }
  }
  __syncthreads();

  // exact fp32 rescore: 16 threads per candidate (arithmetic identical to round 3)
  {
    const int g = t >> 4, c = t & 15;
    const int idx = (int)(~(u32)top16[g]);
    const float iv = invk[idx];
    const float4* kp = (const float4*)(keys + (size_t)idx * DD);
    const float4* qp = (const float4*)(qn + (size_t)b * DD);
    float s = 0.0f;
    for (int j = 0; j < 48; ++j) {
      float4 kv = kp[j * 16 + c];
      float4 qv = qp[j * 16 + c];
      s = fmaf(qv.x, kv.x * iv, s);
      s = fmaf(qv.y, kv.y * iv, s);
      s = fmaf(qv.z, kv.z * iv, s);
      s = fmaf(qv.w, kv.w * iv, s);
    }
    s += __shfl_xor(s, 1); s += __shfl_xor(s, 2);
    s += __shfl_xor(s, 4); s += __shfl_xor(s, 8);
    if (c == 0) exact[g] = s;
  }
  __syncthreads();

  if (w == 0 && l < 16) {  // top-10 of 16 by exact score
    u64 ek = makekey(exact[l], (int)(~(u32)top16[l]));
#pragma unroll 1
    for (int r = 0; r < TOPK; ++r) {
      u64 wb = ek;
#pragma unroll
      for (int off = 1; off < 16; off <<= 1) {
        u64 o = __shfl_xor(wb, off);
        wb = o > wb ? o : wb;
      }
      if (wb == ek) ek = 0;
      if (l == 0) ord[r] = (int)(~(u32)wb);
    }
  }
  __syncthreads();

  // gather raw key rows + indices (as float; flat f32 out buffer)
  for (int r = 0; r < TOPK; ++r) {
    int idx = ord[r];
    if (t == 0) out_idx[b * TOPK + r] = (float)idx;
    const float4* src = (const float4*)(keys + (size_t)idx * DD);
    float4* dst = (float4*)(out_emb + ((size_t)b * TOPK + r) * DD);
#pragma unroll
    for (int c2 = 0; c2 < 3; ++c2) dst[t + c2 * 256] = src[t + c2 * 256];
  }
}

extern "C" void kernel_launch(void* const* d_in, const int* in_sizes, int n_in,
                              void* d_out, int out_size, void* d_ws, size_t ws_size,
                              hipStream_t stream) {
  const float* query = (const float*)d_in[0];
  const float* keys  = (const float*)d_in[1];

  float* ws = (float*)d_ws;
  float* invk = ws;                                  // NK floats
  float* qn   = ws + NK;                             // NQ*DD floats
  u16*   apre = (u16*)(ws + NK + (size_t)NQ * DD);   // KTILES*256*BK bf16 (1.5 MB)
  u64*   cand = (u64*)((char*)(void*)apre + (size_t)KTILES * ATILE_BYTES);  // NQ*1024*CPB u64 (16 MB)

  float* out_emb = (float*)d_out;
  float* out_idx = (float*)d_out + (size_t)NQ * TOPK * DD;

  qnorm_kernel<<<NQ, 256, 0, stream>>>(query, qn, apre);
  gemm_topk<<<NK / BN, 256, 0, stream>>>(apre, keys, invk, cand);
  merge_rescore<<<NQ, 256, 0, stream>>>(cand, qn, keys, invk, out_emb, out_idx);
}